// Round 3
// baseline (466.310 us; speedup 1.0000x reference)
//
#include <hip/hip_runtime.h>
#include <hip/hip_cooperative_groups.h>
#include <math.h>

namespace cg = cooperative_groups;

#define BATCH 2048
#define LATENT 64
#define LOG_2PI 1.8378770664093453f
#define BETA_M1 5.0f
#define LN2 0.69314718055994530942f
// C2 = -0.5 * log2(e)
#define C2 (-0.72134752044448170368f)
#define EXP2F __builtin_amdgcn_exp2f
#define LOG2F __builtin_amdgcn_logf

// ws layout (float offsets):
//   Vt   [128][2048]  Vt[2l][j]=C2*inv, Vt[2l+1][j]=C2*m*inv
//   Tce  [64][2048]   Tce[l][j]=C2*(m^2*inv+lv+LOG2PI)
//   Up   [128][2048]  Up[2l][i]=z^2, Up[2l+1][i]=-2z
//   CE   [2048], KLP [2048]
//   RMP/RSP [4][2048] row-LSE partials (log2 domain)
//   PTC/PKL [1024]    per-block partial sums (no atomics)
//   SM   [64][2048]   fp32 per-(l,i) exp sums (one writer per element)
#define OFF_VT   0
#define OFF_TCE  (128*BATCH)
#define OFF_UP   (OFF_TCE + 64*BATCH)
#define OFF_CE   (OFF_UP + 128*BATCH)
#define OFF_KLP  (OFF_CE + BATCH)
#define OFF_RMP  (OFF_KLP + BATCH)
#define OFF_RSP  (OFF_RMP + 4*BATCH)
#define OFF_PTC  (OFF_RSP + 4*BATCH)
#define OFF_PKL  (OFF_PTC + 1024)
#define OFF_SM   (OFF_PKL + 1024)

// ---------------- Phase P: precompute, 2 j per block (1024 blocks) ----------
__device__ __forceinline__ void phase_p(const float* __restrict__ z,
                                        const float* __restrict__ zm,
                                        const float* __restrict__ zlv,
                                        float* __restrict__ ws, int bx, int t) {
    if (t >= 128) return;
    int w = t >> 6, l = t & 63;
    int j = bx * 2 + w;
    int idx = j * LATENT + l;
    float zv = z[idx], m = zm[idx], lv = zlv[idx];
    float iv  = __expf(-lv);
    float civ = C2 * iv;
    float miv = m * iv;
    float cmv = C2 * miv;
    float cev = C2 * fmaf(m, miv, lv + LOG_2PI);
    ws[OFF_VT  + (2*l)   * BATCH + j] = civ;
    ws[OFF_VT  + (2*l+1) * BATCH + j] = cmv;
    ws[OFF_TCE + l       * BATCH + j] = cev;
    ws[OFF_UP  + (2*l)   * BATCH + j] = zv * zv;
    ws[OFF_UP  + (2*l+1) * BATCH + j] = -2.0f * zv;
    float ce = cev;
    float kl = fmaf(m, m, __expf(lv)) - lv - 1.0f;
    #pragma unroll
    for (int off = 32; off > 0; off >>= 1) {
        ce += __shfl_xor(ce, off, 64);
        kl += __shfl_xor(kl, off, 64);
    }
    if (l == 0) { ws[OFF_CE + j] = ce; ws[OFF_KLP + j] = kl; }
}

// ---------------- dim task: (l, ic) = (bx>>4, bx&15); 128 i x all 2048 j ----
// Threads: ig = t&15 (16 groups x 8 i), js = t>>4 (16 stripes x 128 j).
// Block owns SM[l][i0..i0+128) fully -> plain stores, no atomics.
__device__ __forceinline__ void dim_part(float* __restrict__ ws, int bx, int t,
                                         float (*Dred)[128]) {
    int l = bx >> 4, ic = bx & 15;
    int i0 = ic * 128;
    int ig = t & 15, js = t >> 4;
    int ib = i0 + ig * 8;

    const float* __restrict__ up0 = ws + OFF_UP + (2*l)   * BATCH + ib;
    const float* __restrict__ up1 = ws + OFF_UP + (2*l+1) * BATCH + ib;
    float4 za = *(const float4*)(up0);
    float4 zb = *(const float4*)(up0 + 4);
    float4 na = *(const float4*)(up1);
    float4 nb = *(const float4*)(up1 + 4);
    float z2[8] = {za.x, za.y, za.z, za.w, zb.x, zb.y, zb.z, zb.w};
    float n2[8] = {na.x, na.y, na.z, na.w, nb.x, nb.y, nb.z, nb.w};

    const float4* __restrict__ pc4 = (const float4*)(ws + OFF_VT  + (2*l)   * BATCH + js * 128);
    const float4* __restrict__ pm4 = (const float4*)(ws + OFF_VT  + (2*l+1) * BATCH + js * 128);
    const float4* __restrict__ pe4 = (const float4*)(ws + OFF_TCE + l       * BATCH + js * 128);

    float s[8] = {0.f, 0.f, 0.f, 0.f, 0.f, 0.f, 0.f, 0.f};

    #pragma unroll 2
    for (int q = 0; q < 32; ++q) {
        float4 cc = pc4[q], mm = pm4[q], ee = pe4[q];
        #pragma unroll
        for (int k = 0; k < 8; ++k) {
            s[k] += EXP2F(fmaf(z2[k], cc.x, fmaf(n2[k], mm.x, ee.x)));
            s[k] += EXP2F(fmaf(z2[k], cc.y, fmaf(n2[k], mm.y, ee.y)));
            s[k] += EXP2F(fmaf(z2[k], cc.z, fmaf(n2[k], mm.z, ee.z)));
            s[k] += EXP2F(fmaf(z2[k], cc.w, fmaf(n2[k], mm.w, ee.w)));
        }
    }

    // reduce over js stripes: in-wave bits t[5:4] via shfl, waves via LDS
    #pragma unroll
    for (int off = 16; off < 64; off <<= 1) {
        #pragma unroll
        for (int k = 0; k < 8; ++k)
            s[k] += __shfl_xor(s[k], off, 64);
    }
    int lane = t & 63, w = t >> 6;
    if (lane < 16) {
        #pragma unroll
        for (int k = 0; k < 8; ++k) Dred[w][lane * 8 + k] = s[k];
    }
    __syncthreads();
    if (t < 128) {
        float v = Dred[0][t] + Dred[1][t] + Dred[2][t] + Dred[3][t];
        ws[OFF_SM + l * BATCH + i0 + t] = v;
    }
    __syncthreads();
}

// ---------------- row task: (ig, jq) = (bx>>2, bx&3); 8 i x 512 j, all l ----
__device__ __forceinline__ void row_part(float* __restrict__ ws, int bx, int t,
                                         float* __restrict__ Ups,
                                         float (*RMs)[4], float (*RSs)[4]) {
    int ig = bx >> 2, jq = bx & 3;
    int i0 = ig * 8;
    int j  = jq * 512 + 2 * t;

    // stage Up[*][i0..i0+7] (128 rows x 8 floats = 4KB) into LDS
    #pragma unroll
    for (int p = 0; p < 4; ++p) {
        int f = t + 256 * p;
        Ups[f] = ws[OFF_UP + (f >> 3) * BATCH + i0 + (f & 7)];
    }
    __syncthreads();

    float r0[8], r1[8];
    #pragma unroll
    for (int i = 0; i < 8; ++i) { r0[i] = 0.0f; r1[i] = 0.0f; }

    const float* __restrict__ Vt = ws + OFF_VT;
    for (int l = 0; l < LATENT; ++l) {
        float2 v0 = *(const float2*)(Vt + (2*l)   * BATCH + j);
        float2 v1 = *(const float2*)(Vt + (2*l+1) * BATCH + j);
        const float* __restrict__ ua = Ups + (2*l)   * 8;
        const float* __restrict__ ub = Ups + (2*l+1) * 8;
        #pragma unroll
        for (int i = 0; i < 8; ++i) {
            float a = ua[i], b = ub[i];
            r0[i] = fmaf(a, v0.x, fmaf(b, v1.x, r0[i]));
            r1[i] = fmaf(a, v0.y, fmaf(b, v1.y, r1[i]));
        }
    }

    float2 ce2 = *(const float2*)(ws + OFF_CE + j);
    int lane = t & 63, w = t >> 6;
    #pragma unroll
    for (int i = 0; i < 8; ++i) {
        float a0 = r0[i] + ce2.x, a1 = r1[i] + ce2.y;
        float M = fmaxf(a0, a1);
        float S = EXP2F(a0 - M) + EXP2F(a1 - M);
        #pragma unroll
        for (int off = 32; off > 0; off >>= 1) {
            float Mo = __shfl_xor(M, off, 64);
            float So = __shfl_xor(S, off, 64);
            float mn = fmaxf(M, Mo);
            S = S * EXP2F(M - mn) + So * EXP2F(Mo - mn);
            M = mn;
        }
        if (lane == 0) { RMs[i][w] = M; RSs[i][w] = S; }
    }
    __syncthreads();
    if (t < 8) {
        float M = RMs[t][0], S = RSs[t][0];
        #pragma unroll
        for (int w2 = 1; w2 < 4; ++w2) {
            float Mo = RMs[t][w2], So = RSs[t][w2];
            float mn = fmaxf(M, Mo);
            S = S * EXP2F(M - mn) + So * EXP2F(Mo - mn);
            M = mn;
        }
        ws[OFF_RMP + jq * BATCH + i0 + t] = M;
        ws[OFF_RSP + jq * BATCH + i0 + t] = S;
    }
    __syncthreads();
}

// ---------------- Phase F: per-block partial of tc/kl into PTC/PKL ----------
__device__ __forceinline__ void phase_f(float* __restrict__ ws, int bx, int t,
                                        float* __restrict__ s_tc,
                                        float* __restrict__ s_kl) {
    int gid = bx * 256 + t;
    float acc = 0.0f, kl = 0.0f;
    if (gid < 64 * BATCH) {
        acc = -LOG2F(ws[OFF_SM + gid]);
    } else {
        int i = gid - 64 * BATCH;
        if (i < BATCH) {
            float M = ws[OFF_RMP + i], S = ws[OFF_RSP + i];
            #pragma unroll
            for (int q = 1; q < 4; ++q) {
                float Mo = ws[OFF_RMP + q * BATCH + i];
                float So = ws[OFF_RSP + q * BATCH + i];
                float mn = fmaxf(M, Mo);
                S = S * EXP2F(M - mn) + So * EXP2F(Mo - mn);
                M = mn;
            }
            acc = M + LOG2F(S);
            kl = ws[OFF_KLP + i];
        }
    }
    s_tc[t] = acc; s_kl[t] = kl;
    __syncthreads();
    for (int s2 = 128; s2 > 0; s2 >>= 1) {
        if (t < s2) { s_tc[t] += s_tc[t + s2]; s_kl[t] += s_kl[t + s2]; }
        __syncthreads();
    }
    if (t == 0) { ws[OFF_PTC + bx] = s_tc[0]; ws[OFF_PKL + bx] = s_kl[0]; }
    __syncthreads();
}

__device__ __forceinline__ void assemble(float* __restrict__ ws,
                                         float* __restrict__ out, int t,
                                         float* __restrict__ s_tc,
                                         float* __restrict__ s_kl) {
    float tc = ws[OFF_PTC + t] + ws[OFF_PTC + t + 256]
             + ws[OFF_PTC + t + 512] + ws[OFF_PTC + t + 768];
    float kl = ws[OFF_PKL + t] + ws[OFF_PKL + t + 256]
             + ws[OFF_PKL + t + 512] + ws[OFF_PKL + t + 768];
    s_tc[t] = tc; s_kl[t] = kl;
    __syncthreads();
    for (int s2 = 128; s2 > 0; s2 >>= 1) {
        if (t < s2) { s_tc[t] += s_tc[t + s2]; s_kl[t] += s_kl[t + s2]; }
        __syncthreads();
    }
    if (t == 0)
        out[0] = BETA_M1 * (LN2 * s_tc[0] / (float)BATCH) + 0.5f * (s_kl[0] / (float)BATCH);
}

// ---------------- fused cooperative kernel: 1024 blocks x 256 (4/CU) --------
__global__ __launch_bounds__(256, 4) void fused_kernel(
        const float* __restrict__ z, const float* __restrict__ zm,
        const float* __restrict__ zlv, float* __restrict__ ws,
        float* __restrict__ out) {
    cg::grid_group grid = cg::this_grid();
    __shared__ float Ups[1024];
    __shared__ float Dred[4][128];
    __shared__ float RMs[8][4], RSs[8][4];
    __shared__ float s_tc[256], s_kl[256];

    int bx = blockIdx.x, t = threadIdx.x;

    phase_p(z, zm, zlv, ws, bx, t);
    grid.sync();

    // stagger: co-resident blocks are spaced 256 apart -> bit 8 alternates,
    // mixing exp-heavy (dim) and fma-heavy (row) waves on every CU.
    if (((bx >> 8) & 1) == 0) {
        dim_part(ws, bx, t, Dred);
        row_part(ws, bx, t, Ups, RMs, RSs);
    } else {
        row_part(ws, bx, t, Ups, RMs, RSs);
        dim_part(ws, bx, t, Dred);
    }
    grid.sync();

    phase_f(ws, bx, t, s_tc, s_kl);
    grid.sync();

    if (bx == 0) assemble(ws, out, t, s_tc, s_kl);
}

// ---------------- non-cooperative fallback (same device code) ---------------
__global__ __launch_bounds__(256, 4) void precomp_kernel(
        const float* __restrict__ z, const float* __restrict__ zm,
        const float* __restrict__ zlv, float* __restrict__ ws) {
    phase_p(z, zm, zlv, ws, blockIdx.x, threadIdx.x);
}
__global__ __launch_bounds__(256, 4) void main_kernel(float* __restrict__ ws) {
    __shared__ float Ups[1024];
    __shared__ float Dred[4][128];
    __shared__ float RMs[8][4], RSs[8][4];
    int bx = blockIdx.x, t = threadIdx.x;
    if (((bx >> 8) & 1) == 0) {
        dim_part(ws, bx, t, Dred);
        row_part(ws, bx, t, Ups, RMs, RSs);
    } else {
        row_part(ws, bx, t, Ups, RMs, RSs);
        dim_part(ws, bx, t, Dred);
    }
}
__global__ __launch_bounds__(256, 4) void final_kernel(float* __restrict__ ws) {
    __shared__ float s_tc[256], s_kl[256];
    phase_f(ws, blockIdx.x, threadIdx.x, s_tc, s_kl);
}
__global__ __launch_bounds__(256) void assemble_kernel(float* __restrict__ ws,
                                                       float* __restrict__ out) {
    __shared__ float s_tc[256], s_kl[256];
    assemble(ws, out, threadIdx.x, s_tc, s_kl);
}

extern "C" void kernel_launch(void* const* d_in, const int* in_sizes, int n_in,
                              void* d_out, int out_size, void* d_ws, size_t ws_size,
                              hipStream_t stream) {
    const float* z        = (const float*)d_in[0];
    const float* z_mean   = (const float*)d_in[1];
    const float* z_logvar = (const float*)d_in[2];
    float* out = (float*)d_out;
    float* ws  = (float*)d_ws;

    void* args[] = { (void*)&z, (void*)&z_mean, (void*)&z_logvar,
                     (void*)&ws, (void*)&out };
    hipError_t err = hipLaunchCooperativeKernel((void*)fused_kernel,
                                                dim3(1024), dim3(256),
                                                args, 0, stream);
    if (err != hipSuccess) {
        // fallback: same phases as separate launches
        precomp_kernel<<<1024, 256, 0, stream>>>(z, z_mean, z_logvar, ws);
        main_kernel<<<1024, 256, 0, stream>>>(ws);
        final_kernel<<<1024, 256, 0, stream>>>(ws);
        assemble_kernel<<<1, 256, 0, stream>>>(ws, out);
    }
}

// Round 4
// 126.991 us; speedup vs baseline: 3.6720x; 3.6720x over previous
//
#include <hip/hip_runtime.h>
#include <math.h>

#define BATCH 2048
#define LATENT 64
#define LOG_2PI 1.8378770664093453f
#define BETA_M1 5.0f
#define LN2 0.69314718055994530942f
// C2 = -0.5 * log2(e)
#define C2 (-0.72134752044448170368f)
#define EXP2F __builtin_amdgcn_exp2f
#define LOG2F __builtin_amdgcn_logf

// ws layout (float offsets):
//   Vt   [128][2048]  Vt[2l][j]=C2*inv, Vt[2l+1][j]=C2*m*inv
//   Tce  [64][2048]   Tce[l][j]=C2*(m^2*inv+lv+LOG2PI)
//   Up   [128][2048]  Up[2l][i]=z^2, Up[2l+1][i]=-2z
//   CE   [2048], KLP [2048]
//   RMP/RSP [8][2048] row-LSE partials (log2 domain)
//   PART [16]         PART[0]=tc sum, PART[1]=kl sum, PART[2]=ticket counter
//   SM   [64][2048]   fp32 per-(l,i) exp sums (one writer per element)
#define OFF_VT   0
#define OFF_TCE  (128*BATCH)
#define OFF_UP   (OFF_TCE + 64*BATCH)
#define OFF_CE   (OFF_UP + 128*BATCH)
#define OFF_KLP  (OFF_CE + BATCH)
#define OFF_RMP  (OFF_KLP + BATCH)
#define OFF_RSP  (OFF_RMP + 8*BATCH)
#define OFF_PART (OFF_RSP + 8*BATCH)
#define OFF_SM   (OFF_PART + 16)

// Precompute: grid 128 x 256, each block transposes 16 j x 64 l. (R0-proven.)
__global__ __launch_bounds__(256) void precompute_kernel(const float* __restrict__ z,
                                                         const float* __restrict__ zm,
                                                         const float* __restrict__ zlv,
                                                         float* __restrict__ ws) {
    __shared__ float Tz[16][65], Tm[16][65], Tlv[16][65];
    __shared__ float CEp[16][16], KLp[16][16];
    int t = threadIdx.x, lane = t & 63, w = t >> 6;
    int j0 = blockIdx.x * 16;

    #pragma unroll
    for (int p = 0; p < 4; ++p) {
        int jr = p * 4 + w;
        int idx = (j0 + jr) * LATENT + lane;
        Tz[jr][lane]  = z[idx];
        Tm[jr][lane]  = zm[idx];
        Tlv[jr][lane] = zlv[idx];
    }
    if (blockIdx.x == 0 && t < 16) ws[OFF_PART + t] = 0.0f;
    __syncthreads();

    int jl = t & 15, lg = t >> 4;
    int j = j0 + jl;
    float ce_acc = 0.0f, kl_acc = 0.0f;
    #pragma unroll
    for (int q = 0; q < 4; ++q) {
        int l = q * 16 + lg;
        float zv = Tz[jl][l];
        float m  = Tm[jl][l];
        float lv = Tlv[jl][l];
        float iv  = __expf(-lv);
        float civ = C2 * iv;
        float miv = m * iv;
        float cmv = C2 * miv;
        float cev = C2 * fmaf(m, miv, lv + LOG_2PI);
        ws[OFF_VT  + (2*l)   * BATCH + j] = civ;
        ws[OFF_VT  + (2*l+1) * BATCH + j] = cmv;
        ws[OFF_TCE + l       * BATCH + j] = cev;
        ws[OFF_UP  + (2*l)   * BATCH + j] = zv * zv;
        ws[OFF_UP  + (2*l+1) * BATCH + j] = -2.0f * zv;
        ce_acc += cev;
        kl_acc += fmaf(m, m, __expf(lv)) - lv - 1.0f;
    }
    CEp[lg][jl] = ce_acc;
    KLp[lg][jl] = kl_acc;
    __syncthreads();
    if (t < 16) {
        float ce = 0.0f, kl = 0.0f;
        #pragma unroll
        for (int g = 0; g < 16; ++g) { ce += CEp[g][t]; kl += KLp[g][t]; }
        ws[OFF_CE  + j0 + t] = ce;
        ws[OFF_KLP + j0 + t] = kl;
    }
}

// ---- unified main: 2048 identical blocks, each does one dim sub-task and
// ---- one row sub-task; order staggered by bit 8 of blockIdx so every SIMD
// ---- hosts a mix of exp-heavy (trans pipe) and fma-heavy (VALU pipe) waves.

// dim: (l, ic) = (bx>>5, bx&31). Block owns SM[l][ic*64 .. +64) -- the FULL
// j-sum, so plain stores (no atomics). Threads: 8 i-groups x 32 j-stripes.
__device__ __forceinline__ void dim_part(float* __restrict__ ws, int bx, int t,
                                         float (*Dred)[64]) {
    int l = bx >> 5, ic = bx & 31;
    int i0 = ic * 64;
    int ig = t & 7, js = t >> 3;
    int ib = i0 + ig * 8;

    const float* __restrict__ up0 = ws + OFF_UP + (2*l)   * BATCH + ib;
    const float* __restrict__ up1 = ws + OFF_UP + (2*l+1) * BATCH + ib;
    float4 za = *(const float4*)(up0);
    float4 zb = *(const float4*)(up0 + 4);
    float4 na = *(const float4*)(up1);
    float4 nb = *(const float4*)(up1 + 4);
    float z2[8] = {za.x, za.y, za.z, za.w, zb.x, zb.y, zb.z, zb.w};
    float n2[8] = {na.x, na.y, na.z, na.w, nb.x, nb.y, nb.z, nb.w};

    const float4* __restrict__ pc4 = (const float4*)(ws + OFF_VT  + (2*l)   * BATCH + js * 64);
    const float4* __restrict__ pm4 = (const float4*)(ws + OFF_VT  + (2*l+1) * BATCH + js * 64);
    const float4* __restrict__ pe4 = (const float4*)(ws + OFF_TCE + l       * BATCH + js * 64);

    float s[8] = {0.f, 0.f, 0.f, 0.f, 0.f, 0.f, 0.f, 0.f};

    #pragma unroll 4
    for (int q = 0; q < 16; ++q) {
        float4 cc = pc4[q], mm = pm4[q], ee = pe4[q];
        #pragma unroll
        for (int k = 0; k < 8; ++k) {
            s[k] += EXP2F(fmaf(z2[k], cc.x, fmaf(n2[k], mm.x, ee.x)));
            s[k] += EXP2F(fmaf(z2[k], cc.y, fmaf(n2[k], mm.y, ee.y)));
            s[k] += EXP2F(fmaf(z2[k], cc.z, fmaf(n2[k], mm.z, ee.z)));
            s[k] += EXP2F(fmaf(z2[k], cc.w, fmaf(n2[k], mm.w, ee.w)));
        }
    }

    // reduce the 8 j-stripes within each wave (stripe bits are t[5:3])
    #pragma unroll
    for (int off = 8; off < 64; off <<= 1) {
        #pragma unroll
        for (int k = 0; k < 8; ++k)
            s[k] += __shfl_xor(s[k], off, 64);
    }
    int lane = t & 63, w = t >> 6;
    if (lane < 8) {
        #pragma unroll
        for (int k = 0; k < 8; ++k) Dred[w][lane * 8 + k] = s[k];
    }
    __syncthreads();
    if (t < 64) {
        float v = Dred[0][t] + Dred[1][t] + Dred[2][t] + Dred[3][t];
        ws[OFF_SM + l * BATCH + i0 + t] = v;
    }
    __syncthreads();
}

// row: (ig, jq) = (bx>>3, bx&7): 8 i rows, 256-j chunk, all 64 l.
__device__ __forceinline__ void row_part(float* __restrict__ ws, int bx, int t,
                                         float* __restrict__ Ups,
                                         float (*RMs)[4], float (*RSs)[4]) {
    int ig = bx >> 3, jq = bx & 7;
    int i0 = ig * 8;
    int j  = jq * 256 + t;

    // stage Up[*][i0..i0+7] (128 rows x 8 floats = 4KB) into LDS
    #pragma unroll
    for (int p = 0; p < 4; ++p) {
        int f = t + 256 * p;
        Ups[f] = ws[OFF_UP + (f >> 3) * BATCH + i0 + (f & 7)];
    }
    __syncthreads();

    float r[8];
    #pragma unroll
    for (int i = 0; i < 8; ++i) r[i] = 0.0f;

    const float* __restrict__ Vt = ws + OFF_VT;
    for (int l = 0; l < LATENT; ++l) {
        float v0 = Vt[(2*l)   * BATCH + j];
        float v1 = Vt[(2*l+1) * BATCH + j];
        const float* __restrict__ ua = Ups + (2*l)   * 8;
        const float* __restrict__ ub = Ups + (2*l+1) * 8;
        #pragma unroll
        for (int i = 0; i < 8; ++i)
            r[i] = fmaf(ua[i], v0, fmaf(ub[i], v1, r[i]));
    }

    float ce = ws[OFF_CE + j];
    int lane = t & 63, w = t >> 6;
    #pragma unroll
    for (int i = 0; i < 8; ++i) {
        float M = r[i] + ce;
        float S = 1.0f;
        #pragma unroll
        for (int off = 32; off > 0; off >>= 1) {
            float Mo = __shfl_xor(M, off, 64);
            float So = __shfl_xor(S, off, 64);
            float mn = fmaxf(M, Mo);
            S = S * EXP2F(M - mn) + So * EXP2F(Mo - mn);
            M = mn;
        }
        if (lane == 0) { RMs[i][w] = M; RSs[i][w] = S; }
    }
    __syncthreads();
    if (t < 8) {
        float M = RMs[t][0], S = RSs[t][0];
        #pragma unroll
        for (int w2 = 1; w2 < 4; ++w2) {
            float Mo = RMs[t][w2], So = RSs[t][w2];
            float mn = fmaxf(M, Mo);
            S = S * EXP2F(M - mn) + So * EXP2F(Mo - mn);
            M = mn;
        }
        ws[OFF_RMP + jq * BATCH + i0 + t] = M;
        ws[OFF_RSP + jq * BATCH + i0 + t] = S;
    }
    __syncthreads();
}

// (256, 4): min 4 waves/EU -> VGPR cap 128, enough for the 24-float working
// set (R1/R2's min-waves=8 forced 32 VGPR -> 176-405 MB scratch spills).
__global__ __launch_bounds__(256, 4) void main_kernel(float* __restrict__ ws) {
    __shared__ float Ups[1024];
    __shared__ float Dred[4][64];
    __shared__ float RMs[8][4], RSs[8][4];
    int bx = blockIdx.x, t = threadIdx.x;
    // Co-resident blocks on a CU are spaced ~256 apart -> bit 8 alternates.
    if (((bx >> 8) & 1) == 0) {
        dim_part(ws, bx, t, Dred);
        row_part(ws, bx, t, Ups, RMs, RSs);
    } else {
        row_part(ws, bx, t, Ups, RMs, RSs);
        dim_part(ws, bx, t, Dred);
    }
}

// Finalize: tc = sum_i lqz_i - sum_{l,i} log2(SM[l][i]); kl = sum_i KLP[i].
// Last block (atomic ticket) assembles the scalar output.
__global__ __launch_bounds__(256) void finalize_kernel(float* __restrict__ ws,
                                                       float* __restrict__ out) {
    __shared__ float s_tc[256];
    __shared__ float s_kl[256];
    int t = threadIdx.x;
    int gid = blockIdx.x * 256 + t;

    float acc = 0.0f, kl = 0.0f;
    #pragma unroll
    for (int k = 0; k < 4; ++k) {
        float s = ws[OFF_SM + gid + 32768 * k];
        acc -= LOG2F(s);   // log2 domain; scaled by LN2 at the end
    }

    if (gid < BATCH) {
        int i = gid;
        float M = ws[OFF_RMP + i];
        float S = ws[OFF_RSP + i];
        #pragma unroll
        for (int q = 1; q < 8; ++q) {
            float Mo = ws[OFF_RMP + q * BATCH + i];
            float So = ws[OFF_RSP + q * BATCH + i];
            float mn = fmaxf(M, Mo);
            S = S * EXP2F(M - mn) + So * EXP2F(Mo - mn);
            M = mn;
        }
        acc += M + LOG2F(S);
        kl = ws[OFF_KLP + i];
    }

    s_tc[t] = acc; s_kl[t] = kl;
    __syncthreads();
    for (int s2 = 128; s2 > 0; s2 >>= 1) {
        if (t < s2) { s_tc[t] += s_tc[t + s2]; s_kl[t] += s_kl[t + s2]; }
        __syncthreads();
    }
    if (t == 0) {
        atomicAdd(&ws[OFF_PART + 0], s_tc[0]);
        atomicAdd(&ws[OFF_PART + 1], s_kl[0]);
        __threadfence();
        unsigned int old = atomicAdd((unsigned int*)(ws + OFF_PART + 2), 1u);
        if (old == 127u) {
            float tc  = atomicAdd(&ws[OFF_PART + 0], 0.0f);
            float kl2 = atomicAdd(&ws[OFF_PART + 1], 0.0f);
            out[0] = BETA_M1 * (LN2 * tc / (float)BATCH) + 0.5f * (kl2 / (float)BATCH);
        }
    }
}

extern "C" void kernel_launch(void* const* d_in, const int* in_sizes, int n_in,
                              void* d_out, int out_size, void* d_ws, size_t ws_size,
                              hipStream_t stream) {
    const float* z        = (const float*)d_in[0];
    const float* z_mean   = (const float*)d_in[1];
    const float* z_logvar = (const float*)d_in[2];
    float* out = (float*)d_out;
    float* ws  = (float*)d_ws;

    precompute_kernel<<<128, 256, 0, stream>>>(z, z_mean, z_logvar, ws);
    main_kernel<<<2048, 256, 0, stream>>>(ws);
    finalize_kernel<<<128, 256, 0, stream>>>(ws, out);
}

// Round 5
// 123.843 us; speedup vs baseline: 3.7653x; 1.0254x over previous
//
#include <hip/hip_runtime.h>
#include <math.h>

#define BATCH 2048
#define LATENT 64
#define LOG_2PI 1.8378770664093453f
#define BETA_M1 5.0f
#define LN2 0.69314718055994530942f
// C2 = -0.5 * log2(e)
#define C2 (-0.72134752044448170368f)
#define EXP2F __builtin_amdgcn_exp2f
#define LOG2F __builtin_amdgcn_logf

// ws layout (float offsets):
//   Vt   [128][2048]  Vt[2l][j]=C2*inv, Vt[2l+1][j]=C2*m*inv
//   Tce  [64][2048]   Tce[l][j]=C2*(m^2*inv+lv+LOG2PI)
//   Up   [128][2048]  Up[2l][i]=z^2, Up[2l+1][i]=-2z
//   CE   [2048], KLP [2048]
//   RMP/RSP [2][2048] row-LSE partials (log2 domain), one per j-half
//   PART [16]         PART[0]=tc sum, PART[1]=kl sum, PART[2]=ticket counter
//   SM   [64][2048]   fp32 per-(l,i) exp sums (one writer per element)
#define OFF_VT   0
#define OFF_TCE  (128*BATCH)
#define OFF_UP   (OFF_TCE + 64*BATCH)
#define OFF_CE   (OFF_UP + 128*BATCH)
#define OFF_KLP  (OFF_CE + BATCH)
#define OFF_RMP  (OFF_KLP + BATCH)
#define OFF_RSP  (OFF_RMP + 2*BATCH)
#define OFF_PART (OFF_RSP + 2*BATCH)
#define OFF_SM   (OFF_PART + 16)

// Precompute: grid 128 x 256, each block transposes 16 j x 64 l. (R0-proven.)
__global__ __launch_bounds__(256) void precompute_kernel(const float* __restrict__ z,
                                                         const float* __restrict__ zm,
                                                         const float* __restrict__ zlv,
                                                         float* __restrict__ ws) {
    __shared__ float Tz[16][65], Tm[16][65], Tlv[16][65];
    __shared__ float CEp[16][16], KLp[16][16];
    int t = threadIdx.x, lane = t & 63, w = t >> 6;
    int j0 = blockIdx.x * 16;

    #pragma unroll
    for (int p = 0; p < 4; ++p) {
        int jr = p * 4 + w;
        int idx = (j0 + jr) * LATENT + lane;
        Tz[jr][lane]  = z[idx];
        Tm[jr][lane]  = zm[idx];
        Tlv[jr][lane] = zlv[idx];
    }
    if (blockIdx.x == 0 && t < 16) ws[OFF_PART + t] = 0.0f;
    __syncthreads();

    int jl = t & 15, lg = t >> 4;
    int j = j0 + jl;
    float ce_acc = 0.0f, kl_acc = 0.0f;
    #pragma unroll
    for (int q = 0; q < 4; ++q) {
        int l = q * 16 + lg;
        float zv = Tz[jl][l];
        float m  = Tm[jl][l];
        float lv = Tlv[jl][l];
        float iv  = __expf(-lv);
        float civ = C2 * iv;
        float miv = m * iv;
        float cmv = C2 * miv;
        float cev = C2 * fmaf(m, miv, lv + LOG_2PI);
        ws[OFF_VT  + (2*l)   * BATCH + j] = civ;
        ws[OFF_VT  + (2*l+1) * BATCH + j] = cmv;
        ws[OFF_TCE + l       * BATCH + j] = cev;
        ws[OFF_UP  + (2*l)   * BATCH + j] = zv * zv;
        ws[OFF_UP  + (2*l+1) * BATCH + j] = -2.0f * zv;
        ce_acc += cev;
        kl_acc += fmaf(m, m, __expf(lv)) - lv - 1.0f;
    }
    CEp[lg][jl] = ce_acc;
    KLp[lg][jl] = kl_acc;
    __syncthreads();
    if (t < 16) {
        float ce = 0.0f, kl = 0.0f;
        #pragma unroll
        for (int g = 0; g < 16; ++g) { ce += CEp[g][t]; kl += KLp[g][t]; }
        ws[OFF_CE  + j0 + t] = ce;
        ws[OFF_KLP + j0 + t] = kl;
    }
}

// ---- main: 2560 single-task blocks. Tasks interleaved 4 dim : 1 row in
// ---- dispatch order so every CU hosts a mix of exp-heavy (trans pipe) and
// ---- fma-heavy (VALU pipe) waves for the whole kernel. No cross-phase
// ---- barriers inside a block (R4's dim+row fusion convoyed all 4 waves).

// dim task d in [0,2048): (l, ic) = (d>>5, d&31). Block owns the FULL j-sum
// for SM[l][ic*64 .. +64) -> plain stores, no atomics.
// Threads: ig = t&7 (8 groups x 8 i), js = t>>3 (32 stripes x 64 j).
__device__ __forceinline__ void dim_part(float* __restrict__ ws, int d, int t,
                                         float (*Dred)[64]) {
    int l = d >> 5, ic = d & 31;
    int i0 = ic * 64;
    int ig = t & 7, js = t >> 3;
    int ib = i0 + ig * 8;

    const float* __restrict__ up0 = ws + OFF_UP + (2*l)   * BATCH + ib;
    const float* __restrict__ up1 = ws + OFF_UP + (2*l+1) * BATCH + ib;
    float4 za = *(const float4*)(up0);
    float4 zb = *(const float4*)(up0 + 4);
    float4 na = *(const float4*)(up1);
    float4 nb = *(const float4*)(up1 + 4);
    float z2[8] = {za.x, za.y, za.z, za.w, zb.x, zb.y, zb.z, zb.w};
    float n2[8] = {na.x, na.y, na.z, na.w, nb.x, nb.y, nb.z, nb.w};

    const float4* __restrict__ pc4 = (const float4*)(ws + OFF_VT  + (2*l)   * BATCH + js * 64);
    const float4* __restrict__ pm4 = (const float4*)(ws + OFF_VT  + (2*l+1) * BATCH + js * 64);
    const float4* __restrict__ pe4 = (const float4*)(ws + OFF_TCE + l       * BATCH + js * 64);

    float s[8] = {0.f, 0.f, 0.f, 0.f, 0.f, 0.f, 0.f, 0.f};

    #pragma unroll 4
    for (int q = 0; q < 16; ++q) {
        float4 cc = pc4[q], mm = pm4[q], ee = pe4[q];
        #pragma unroll
        for (int k = 0; k < 8; ++k) {
            s[k] += EXP2F(fmaf(z2[k], cc.x, fmaf(n2[k], mm.x, ee.x)));
            s[k] += EXP2F(fmaf(z2[k], cc.y, fmaf(n2[k], mm.y, ee.y)));
            s[k] += EXP2F(fmaf(z2[k], cc.z, fmaf(n2[k], mm.z, ee.z)));
            s[k] += EXP2F(fmaf(z2[k], cc.w, fmaf(n2[k], mm.w, ee.w)));
        }
    }

    // reduce the 8 j-stripes within each wave (stripe bits are t[5:3])
    #pragma unroll
    for (int off = 8; off < 64; off <<= 1) {
        #pragma unroll
        for (int k = 0; k < 8; ++k)
            s[k] += __shfl_xor(s[k], off, 64);
    }
    int lane = t & 63, w = t >> 6;
    if (lane < 8) {
        #pragma unroll
        for (int k = 0; k < 8; ++k) Dred[w][lane * 8 + k] = s[k];
    }
    __syncthreads();
    if (t < 64) {
        float v = Dred[0][t] + Dred[1][t] + Dred[2][t] + Dred[3][t];
        ws[OFF_SM + l * BATCH + i0 + t] = v;
    }
}

// row task r in [0,512): (ig, jh) = (r>>1, r&1): 8 i rows, 1024-j half,
// all 64 l. 4 j per thread via float4 (R0-proven path, 56 VGPR).
__device__ __forceinline__ void row_part(float* __restrict__ ws, int r, int t,
                                         float* __restrict__ Ups,
                                         float (*RMs)[4], float (*RSs)[4]) {
    int ig = r >> 1, jh = r & 1;
    int i0 = ig * 8;
    int jb = jh * 1024 + 4 * t;

    // stage Up[*][i0..i0+7] (128 rows x 8 floats = 4KB) into LDS
    #pragma unroll
    for (int p = 0; p < 4; ++p) {
        int f = t + 256 * p;
        Ups[f] = ws[OFF_UP + (f >> 3) * BATCH + i0 + (f & 7)];
    }
    __syncthreads();

    float acc[8][4];
    #pragma unroll
    for (int i = 0; i < 8; ++i)
        acc[i][0] = acc[i][1] = acc[i][2] = acc[i][3] = 0.0f;

    const float* __restrict__ Vt = ws + OFF_VT;
    for (int l = 0; l < LATENT; ++l) {
        float4 v0 = *(const float4*)(Vt + (2*l)   * BATCH + jb);
        float4 v1 = *(const float4*)(Vt + (2*l+1) * BATCH + jb);
        const float* __restrict__ ua = Ups + (2*l)   * 8;
        const float* __restrict__ ub = Ups + (2*l+1) * 8;
        #pragma unroll
        for (int i = 0; i < 8; ++i) {
            float a = ua[i], b = ub[i];
            acc[i][0] = fmaf(a, v0.x, fmaf(b, v1.x, acc[i][0]));
            acc[i][1] = fmaf(a, v0.y, fmaf(b, v1.y, acc[i][1]));
            acc[i][2] = fmaf(a, v0.z, fmaf(b, v1.z, acc[i][2]));
            acc[i][3] = fmaf(a, v0.w, fmaf(b, v1.w, acc[i][3]));
        }
    }

    float4 ce4 = *(const float4*)(ws + OFF_CE + jb);
    int lane = t & 63, w = t >> 6;
    #pragma unroll
    for (int i = 0; i < 8; ++i) {
        float rc0 = acc[i][0] + ce4.x, rc1 = acc[i][1] + ce4.y;
        float rc2 = acc[i][2] + ce4.z, rc3 = acc[i][3] + ce4.w;
        float M = fmaxf(fmaxf(rc0, rc1), fmaxf(rc2, rc3));
        float S = EXP2F(rc0 - M) + EXP2F(rc1 - M)
                + EXP2F(rc2 - M) + EXP2F(rc3 - M);
        #pragma unroll
        for (int off = 32; off > 0; off >>= 1) {
            float Mo = __shfl_xor(M, off, 64);
            float So = __shfl_xor(S, off, 64);
            float mn = fmaxf(M, Mo);
            S = S * EXP2F(M - mn) + So * EXP2F(Mo - mn);
            M = mn;
        }
        if (lane == 0) { RMs[i][w] = M; RSs[i][w] = S; }
    }
    __syncthreads();
    if (t < 8) {
        float M = RMs[t][0], S = RSs[t][0];
        #pragma unroll
        for (int w2 = 1; w2 < 4; ++w2) {
            float Mo = RMs[t][w2], So = RSs[t][w2];
            float mn = fmaxf(M, Mo);
            S = S * EXP2F(M - mn) + So * EXP2F(Mo - mn);
            M = mn;
        }
        ws[OFF_RMP + jh * BATCH + i0 + t] = M;
        ws[OFF_RSP + jh * BATCH + i0 + t] = S;
    }
}

// (256, 4): min 4 waves/EU -> VGPR cap 128; working sets are 24-32 floats
// (R1/R2 lesson: min-waves=8 forced 32 VGPR -> scratch spill catastrophe).
__global__ __launch_bounds__(256, 4) void main_kernel(float* __restrict__ ws) {
    __shared__ float Ups[1024];
    __shared__ float Dred[4][64];
    __shared__ float RMs[8][4], RSs[8][4];
    int bx = blockIdx.x, t = threadIdx.x;
    int m = bx % 5, q = bx / 5;          // 4 dim : 1 row interleave
    if (m < 4) dim_part(ws, q * 4 + m, t, Dred);
    else       row_part(ws, q, t, Ups, RMs, RSs);
}

// Finalize: tc = sum_i lqz_i - sum_{l,i} log2(SM[l][i]); kl = sum_i KLP[i].
// Last block (atomic ticket) assembles the scalar output.
__global__ __launch_bounds__(256) void finalize_kernel(float* __restrict__ ws,
                                                       float* __restrict__ out) {
    __shared__ float s_tc[256];
    __shared__ float s_kl[256];
    int t = threadIdx.x;
    int gid = blockIdx.x * 256 + t;

    float acc = 0.0f, kl = 0.0f;
    #pragma unroll
    for (int k = 0; k < 4; ++k) {
        float s = ws[OFF_SM + gid + 32768 * k];
        acc -= LOG2F(s);   // log2 domain; scaled by LN2 at the end
    }

    if (gid < BATCH) {
        int i = gid;
        float M0 = ws[OFF_RMP + i], M1 = ws[OFF_RMP + BATCH + i];
        float S0 = ws[OFF_RSP + i], S1 = ws[OFF_RSP + BATCH + i];
        float mn = fmaxf(M0, M1);
        acc += mn + LOG2F(S0 * EXP2F(M0 - mn) + S1 * EXP2F(M1 - mn));
        kl = ws[OFF_KLP + i];
    }

    s_tc[t] = acc; s_kl[t] = kl;
    __syncthreads();
    for (int s2 = 128; s2 > 0; s2 >>= 1) {
        if (t < s2) { s_tc[t] += s_tc[t + s2]; s_kl[t] += s_kl[t + s2]; }
        __syncthreads();
    }
    if (t == 0) {
        atomicAdd(&ws[OFF_PART + 0], s_tc[0]);
        atomicAdd(&ws[OFF_PART + 1], s_kl[0]);
        __threadfence();
        unsigned int old = atomicAdd((unsigned int*)(ws + OFF_PART + 2), 1u);
        if (old == 127u) {
            float tc  = atomicAdd(&ws[OFF_PART + 0], 0.0f);
            float kl2 = atomicAdd(&ws[OFF_PART + 1], 0.0f);
            out[0] = BETA_M1 * (LN2 * tc / (float)BATCH) + 0.5f * (kl2 / (float)BATCH);
        }
    }
}

extern "C" void kernel_launch(void* const* d_in, const int* in_sizes, int n_in,
                              void* d_out, int out_size, void* d_ws, size_t ws_size,
                              hipStream_t stream) {
    const float* z        = (const float*)d_in[0];
    const float* z_mean   = (const float*)d_in[1];
    const float* z_logvar = (const float*)d_in[2];
    float* out = (float*)d_out;
    float* ws  = (float*)d_ws;

    precompute_kernel<<<128, 256, 0, stream>>>(z, z_mean, z_logvar, ws);
    main_kernel<<<2560, 256, 0, stream>>>(ws);
    finalize_kernel<<<128, 256, 0, stream>>>(ws, out);
}